// Round 6
// baseline (233.001 us; speedup 1.0000x reference)
//
#include <hip/hip_runtime.h>
#include <hip/hip_fp16.h>
#include <math.h>

#define NEDGES 2097152
#define CAPB8  4608    /* per-(graph,eighth) bucket cap: mean 4096, sigma~64 -> +8 sigma */
#define CAPC   5120    /* LDS CSR cap: 4608 + row-pad<=384 -> 4992, +128 slack           */

/* ws layout (bytes) */
#define OFF_GFILL 0u          /* int[512] per-bucket fill                   */
#define OFF_ARR1  2048u       /* int[64]  dis-exchange flags                */
#define OFF_ARR2  2304u       /* int[64]  h1-exchange flags                 */
#define OFF_ARR3  2560u       /* int[64]  pool/tail flags                   */
#define OFF_POOL8 4096u       /* float[64*8*32] = 65536 -> 69632            */
#define OFF_DIS   69632u      /* float[65536] = 262144 -> 331776            */
#define OFF_H1G   331776u     /* float[65536*32] = 8388608 -> 8720384       */
#define OFF_EBUF  8720384u    /* uint[512*CAPB8] = 9437184 -> 18157568      */

__device__ __forceinline__ float ftanh(float x) {
    float e = __expf(2.f * x);
    return 1.f - 2.f * __builtin_amdgcn_rcpf(e + 1.f);
}

/* read channels 4q..4q+3 of swizzled f16x2 row r */
__device__ __forceinline__ float4 ld4h(const unsigned int* hs, int r, int q) {
    uint2 u = *(const uint2*)(hs + r * 16 + ((q ^ (r & 7)) << 1));
    float2 fa = __half22float2(*(const __half2*)&u.x);
    float2 fb = __half22float2(*(const __half2*)&u.y);
    return make_float4(fa.x, fa.y, fb.x, fb.y);
}
__device__ __forceinline__ uint2 pk4h(float a, float b, float c, float d) {
    __half2 h0 = __floats2half2_rn(a, b);
    __half2 h1 = __floats2half2_rn(c, d);
    return make_uint2(*(unsigned int*)&h0, *(unsigned int*)&h1);
}

/* ---- bucket edges by (graph, dst-eighth): 512 buckets, block-local counting sort ---- */
__global__ void k_bucket(const int* __restrict__ src, const int* __restrict__ dst,
                         int* __restrict__ gfill, unsigned int* __restrict__ ebuf) {
    __shared__ unsigned int sorted[8192];
    __shared__ int hist[512], lexcl[512], gbase[512], lfill[512];
    __shared__ int wsum[4];
    int t = threadIdx.x;
    hist[t] = 0; hist[t + 256] = 0; lfill[t] = 0; lfill[t + 256] = 0;
    __syncthreads();

    const int4* src4 = (const int4*)(src + blockIdx.x * 8192);
    const int4* dst4 = (const int4*)(dst + blockIdx.x * 8192);
    unsigned int pk[32];
    #pragma unroll
    for (int k = 0; k < 8; k++) {
        int4 s4 = src4[k * 256 + t];
        int4 d4 = dst4[k * 256 + t];
        int ss[4] = { s4.x, s4.y, s4.z, s4.w };
        int dd[4] = { d4.x, d4.y, d4.z, d4.w };
        #pragma unroll
        for (int j = 0; j < 4; j++) {
            int g = ss[j] >> 10;
            /* pack: src_local | dst_local<<10 | g<<20 ; bucket id = pk>>17 */
            pk[k * 4 + j] = (unsigned int)((ss[j] & 1023) | ((dd[j] & 1023) << 10) | (g << 20));
            atomicAdd(&hist[pk[k * 4 + j] >> 17], 1);
        }
    }
    __syncthreads();

    /* 512-wide exclusive scan: thread t owns pair (2t, 2t+1) */
    int h0 = hist[2 * t], h1p = hist[2 * t + 1];
    int s = h0 + h1p;
    int lane = t & 63, wid = t >> 6;
    int xx = s;
    #pragma unroll
    for (int off = 1; off < 64; off <<= 1) {
        int y = __shfl_up(xx, off, 64);
        if (lane >= off) xx += y;
    }
    if (lane == 63) wsum[wid] = xx;
    __syncthreads();
    {
        int pre = 0;
        for (int w = 0; w < wid; w++) pre += wsum[w];
        int P = pre + xx - s;
        lexcl[2 * t] = P;
        lexcl[2 * t + 1] = P + h0;
        gbase[2 * t] = atomicAdd(&gfill[2 * t], h0);
        gbase[2 * t + 1] = atomicAdd(&gfill[2 * t + 1], h1p);
    }
    __syncthreads();

    #pragma unroll
    for (int k = 0; k < 32; k++) {
        int b = pk[k] >> 17;
        int pos = lexcl[b] + atomicAdd(&lfill[b], 1);
        sorted[pos] = pk[k];
    }
    __syncthreads();
    for (int i = t; i < 8192; i += 256) {
        unsigned int p = sorted[i];
        int b = p >> 17;
        ebuf[(size_t)b * CAPB8 + gbase[b] + (i - lexcl[b])] = p;
    }
}

/* ---- eighth-graph GCN: 512 blocks x 1024 thr, 77.4 KB LDS + <=64 VGPR
   (forced by launch_bounds) -> 2 blocks/CU guaranteed -> all 512 blocks
   co-resident -> flag syncs are safe by construction. Sibling blocks of a
   graph share blk&63 -> same XCD (L2-local dis/h1 exchange, R1-proven). ---- */
__global__ __launch_bounds__(1024, 8) void k_gcn(
        const float* __restrict__ x,
        const float* __restrict__ W1, const float* __restrict__ b1,
        const float* __restrict__ W2, const float* __restrict__ b2,
        const float* __restrict__ Wl, const float* __restrict__ bl,
        const float* __restrict__ Wp, const float* __restrict__ bp,
        const float* __restrict__ Vw1, const float* __restrict__ Vb1,
        const float* __restrict__ Vw2, const float* __restrict__ Vb2,
        const float* __restrict__ Vw3, const float* __restrict__ Vb3,
        const float* __restrict__ Cw1, const float* __restrict__ Cb1,
        const float* __restrict__ Cw2, const float* __restrict__ Cb2,
        const float* __restrict__ share,
        const unsigned int* __restrict__ ebuf, const int* __restrict__ gfill,
        float* __restrict__ disg, float* __restrict__ h1g,
        int* __restrict__ arr1, int* __restrict__ arr2, int* __restrict__ arr3,
        float* __restrict__ pooled8, float* __restrict__ out) {
    __shared__ unsigned int hsLh[1025 * 16];            /* 65600 B, row 1024 = zeros */
    __shared__ __align__(16) unsigned short lcsr[CAPC]; /* 10240 B */
    __shared__ int hist[128], lrow[128], lfill[128];    /* 1536 B  */
    __shared__ int wsum[2];
    /* total 77,392 B -> 2 blocks/CU */

    int t = threadIdx.x;
    int g = blockIdx.x & 63, oct = blockIdx.x >> 6;
    int bkt = (g << 3) | oct;
    int cnt = gfill[bkt];
    const unsigned int* eb = ebuf + (size_t)bkt * CAPB8;

    /* preload own x row; latency hides under the edge scan */
    float inr[16];
    {
        const float4* in4 = (const float4*)(x + ((size_t)((g << 10) + t)) * 16);
        #pragma unroll
        for (int k = 0; k < 4; k++) {
            float4 v = in4[k];
            inr[4*k] = v.x; inr[4*k+1] = v.y; inr[4*k+2] = v.z; inr[4*k+3] = v.w;
        }
    }

    if (t < 128) { hist[t] = 0; lfill[t] = 0; }
    if (t < 16) hsLh[1024 * 16 + t] = 0u;               /* zero row for pad */
    __syncthreads();

    /* pass 1: in-degree hist over own bucket (= full in-degree: bucket owns dst) */
    for (int i = t; i < cnt; i += 1024) atomicAdd(&hist[(eb[i] >> 10) & 127], 1);
    __syncthreads();

    /* publish this eighth's dis, release flag 1 */
    int dq = 0, r4 = 0;
    if (t < 128) {
        dq = hist[t]; r4 = (dq + 3) & ~3;
        disg[(g << 10) + (oct << 7) + t] = rsqrtf((float)(dq + 1));
    }
    __syncthreads();   /* drains vmem before release */
    if (t == 0)
        __hip_atomic_fetch_add(arr1 + g, 1, __ATOMIC_RELEASE, __HIP_MEMORY_SCOPE_AGENT);

    /* exclusive scan of 4-aligned degrees (128 entries, 2 waves) */
    int lane = t & 63, wid = t >> 6;
    int xx = r4;
    #pragma unroll
    for (int off = 1; off < 64; off <<= 1) {
        int y = __shfl_up(xx, off, 64);
        if (lane >= off) xx += y;
    }
    if (t < 128 && lane == 63) wsum[wid] = xx;
    __syncthreads();
    if (t < 128) {
        int pre = (wid == 1) ? wsum[0] : 0;
        lrow[t] = pre + xx - r4;
        lfill[t] = 0;
    }
    __syncthreads();

    /* pass 2: scatter own bucket into LDS CSR; pad rows to x4 (overlaps peers) */
    for (int i = t; i < cnt; i += 1024) {
        unsigned int v = eb[i];
        int dl = (v >> 10) & 127;
        int pos = lrow[dl] + atomicAdd(&lfill[dl], 1);
        lcsr[pos] = (unsigned short)(v & 1023);
    }
    if (t < 128) {
        int st = lrow[t];
        for (int i = dq; i < r4; i++) lcsr[st + i] = 1024;
    }

    /* wait for all 8 eighths' dis */
    if (t == 0) {
        while (__hip_atomic_load(arr1 + g, __ATOMIC_RELAXED, __HIP_MEMORY_SCOPE_AGENT) < 8) {}
        (void)__hip_atomic_load(arr1 + g, __ATOMIC_ACQUIRE, __HIP_MEMORY_SCOPE_AGENT);
    }
    __syncthreads();

    float dis_t = disg[(g << 10) + t];
    int sw = t & 7;

    /* stage hs1 = dis * (x @ W1^T) for ALL 1024 nodes, f16x2 swizzled */
    #pragma unroll
    for (int o4 = 0; o4 < 8; o4++) {
        float r[4];
        #pragma unroll
        for (int j = 0; j < 4; j++) {
            int o = o4 * 4 + j;
            float s = 0.f;
            #pragma unroll
            for (int k = 0; k < 16; k++) s += inr[k] * W1[o * 16 + k];
            r[j] = s * dis_t;
        }
        *(uint2*)&hsLh[t * 16 + ((o4 ^ sw) << 1)] = pk4h(r[0], r[1], r[2], r[3]);
    }
    __syncthreads();

    /* layer-1 gather: own 128 nodes, 8 lanes/node, ONE pass; h1 -> global f32 */
    int q = t & 7, grp = t >> 3;                /* grp in [0,128) */
    int ln = (oct << 7) + grp;                  /* graph-local node id */
    {
        int d = hist[grp];
        float dn = rsqrtf((float)(d + 1));
        int st = lrow[grp];
        float4 acc = ld4h(hsLh, ln, q);         /* self loop */
        const ushort4* c4 = (const ushort4*)(lcsr + st);
        int d4 = (d + 3) >> 2;
        for (int i = 0; i < d4; i++) {
            ushort4 ss = c4[i];
            float4 v0 = ld4h(hsLh, ss.x, q);
            float4 v1 = ld4h(hsLh, ss.y, q);
            float4 v2 = ld4h(hsLh, ss.z, q);
            float4 v3 = ld4h(hsLh, ss.w, q);
            acc.x += (v0.x + v1.x) + (v2.x + v3.x);
            acc.y += (v0.y + v1.y) + (v2.y + v3.y);
            acc.z += (v0.z + v1.z) + (v2.z + v3.z);
            acc.w += (v0.w + v1.w) + (v2.w + v3.w);
        }
        float4 bb = ((const float4*)b1)[q];
        float4 r;
        r.x = ftanh(dn * acc.x + bb.x);
        r.y = ftanh(dn * acc.y + bb.y);
        r.z = ftanh(dn * acc.z + bb.z);
        r.w = ftanh(dn * acc.w + bb.w);
        ((float4*)h1g)[((size_t)(g << 10) + ln) * 8 + q] = r;
    }
    __syncthreads();   /* drain h1g stores */
    if (t == 0) {
        __hip_atomic_fetch_add(arr2 + g, 1, __ATOMIC_RELEASE, __HIP_MEMORY_SCOPE_AGENT);
        while (__hip_atomic_load(arr2 + g, __ATOMIC_RELAXED, __HIP_MEMORY_SCOPE_AGENT) < 8) {}
        (void)__hip_atomic_load(arr2 + g, __ATOMIC_ACQUIRE, __HIP_MEMORY_SCOPE_AGENT);
    }
    __syncthreads();

    /* read full h1 row for node t, stage hs2 = dis * (h1 @ W2^T), f16 */
    {
        float r2[32];
        const float4* h4 = (const float4*)(h1g + ((size_t)(g << 10) + t) * 32);
        #pragma unroll
        for (int k = 0; k < 8; k++) {
            float4 v = h4[k];
            r2[4*k] = v.x; r2[4*k+1] = v.y; r2[4*k+2] = v.z; r2[4*k+3] = v.w;
        }
        #pragma unroll
        for (int o4 = 0; o4 < 8; o4++) {
            float r[4];
            #pragma unroll
            for (int j = 0; j < 4; j++) {
                int o = o4 * 4 + j;
                float s = 0.f;
                #pragma unroll
                for (int k = 0; k < 32; k++) s += r2[k] * W2[o * 32 + k];
                r[j] = s * dis_t;
            }
            *(uint2*)&hsLh[t * 16 + ((o4 ^ sw) << 1)] = pk4h(r[0], r[1], r[2], r[3]);
        }
    }
    __syncthreads();

    /* layer-2 gather -> h2 in registers */
    float4 h2r;
    {
        int d = hist[grp];
        float dn = rsqrtf((float)(d + 1));
        int st = lrow[grp];
        float4 acc = ld4h(hsLh, ln, q);
        const ushort4* c4 = (const ushort4*)(lcsr + st);
        int d4 = (d + 3) >> 2;
        for (int i = 0; i < d4; i++) {
            ushort4 ss = c4[i];
            float4 v0 = ld4h(hsLh, ss.x, q);
            float4 v1 = ld4h(hsLh, ss.y, q);
            float4 v2 = ld4h(hsLh, ss.z, q);
            float4 v3 = ld4h(hsLh, ss.w, q);
            acc.x += (v0.x + v1.x) + (v2.x + v3.x);
            acc.y += (v0.y + v1.y) + (v2.y + v3.y);
            acc.z += (v0.z + v1.z) + (v2.z + v3.z);
            acc.w += (v0.w + v1.w) + (v2.w + v3.w);
        }
        float4 bb = ((const float4*)b2)[q];
        h2r.x = ftanh(dn * acc.x + bb.x);
        h2r.y = ftanh(dn * acc.y + bb.y);
        h2r.z = ftanh(dn * acc.z + bb.z);
        h2r.w = ftanh(dn * acc.w + bb.w);
    }
    __syncthreads();

    /* write h2 (f16) for own 128 rows */
    *(uint2*)&hsLh[ln * 16 + ((q ^ (ln & 7)) << 1)] = pk4h(h2r.x, h2r.y, h2r.z, h2r.w);
    __syncthreads();

    /* h3 = tanh(h2 @ Wl^T + bl); pool own 128 nodes (32 segs x 4 nodes) */
    int o = t & 31, seg = t >> 5;
    float ps = 0.f;
    {
        float wlr[32];
        #pragma unroll
        for (int k = 0; k < 32; k++) wlr[k] = Wl[o * 32 + k];
        float blv = bl[o];
        #pragma unroll
        for (int j = 0; j < 4; j++) {
            int row = (oct << 7) + seg * 4 + j;
            float s = blv;
            #pragma unroll
            for (int p2 = 0; p2 < 8; p2++) {
                float4 v = ld4h(hsLh, row, p2);
                s += v.x * wlr[4*p2] + v.y * wlr[4*p2+1] + v.z * wlr[4*p2+2] + v.w * wlr[4*p2+3];
            }
            ps += ftanh(s);
        }
    }
    float* psum = (float*)lcsr;   /* CSR dead now */
    psum[t] = ps;
    __syncthreads();
    if (t < 32) {
        float tot = 0.f;
        for (int s2 = 0; s2 < 32; s2++) tot += psum[s2 * 32 + t];
        pooled8[((g << 3) + oct) * 32 + t] = tot;
    }
    __syncthreads();   /* drain pooled8 stores */
    if (t == 0)
        __hip_atomic_fetch_add(arr3 + g, 1, __ATOMIC_RELEASE, __HIP_MEMORY_SCOPE_AGENT);

    /* oct-0 block runs the per-graph MLP tail */
    if (oct == 0) {
        if (t == 0) {
            while (__hip_atomic_load(arr3 + g, __ATOMIC_RELAXED, __HIP_MEMORY_SCOPE_AGENT) < 8) {}
            (void)__hip_atomic_load(arr3 + g, __ATOMIC_ACQUIRE, __HIP_MEMORY_SCOPE_AGENT);
        }
        __syncthreads();
        if (t < 32) {
            int j = t;
            float p = 0.f;
            #pragma unroll
            for (int k = 0; k < 8; k++) p += pooled8[((g << 3) + k) * 32 + j];
            float h1v = bp[j];
            #pragma unroll
            for (int k = 0; k < 32; k++) h1v += Wp[j * 32 + k] * __shfl(p, k, 32);
            float s0 = share[g * 64 + j];
            float s1 = share[g * 64 + 32 + j];
            float t1 = Vb1[j];
            #pragma unroll
            for (int k = 0; k < 32; k++) {
                t1 += Vw1[j * 64 + k] * __shfl(s0, k, 32);
                t1 += Vw1[j * 64 + 32 + k] * __shfl(s1, k, 32);
            }
            t1 = tanhf(t1);
            float t2 = Vb2[j];
            #pragma unroll
            for (int k = 0; k < 32; k++) t2 += Vw2[j * 32 + k] * __shfl(t1, k, 32);
            t2 = tanhf(t2);
            float h2v = Vb3[j];
            #pragma unroll
            for (int k = 0; k < 32; k++) h2v += Vw3[j * 32 + k] * __shfl(t2, k, 32);
            float z = Cb1[j];
            #pragma unroll
            for (int k = 0; k < 32; k++) {
                z += Cw1[j * 64 + k] * __shfl(h1v, k, 32);
                z += Cw1[j * 64 + 32 + k] * __shfl(h2v, k, 32);
            }
            z = tanhf(z);
            float v = Cw2[j] * z;
            v += __shfl_down(v, 16, 32); v += __shfl_down(v, 8, 32);
            v += __shfl_down(v, 4, 32);  v += __shfl_down(v, 2, 32);
            v += __shfl_down(v, 1, 32);
            if (j == 0) out[g] = v + Cb2[0];
        }
    }
}

extern "C" void kernel_launch(void* const* d_in, const int* in_sizes, int n_in,
                              void* d_out, int out_size, void* d_ws, size_t ws_size,
                              hipStream_t stream) {
    const float* x     = (const float*)d_in[0];
    const int*   ei    = (const int*)d_in[1];
    const float* share = (const float*)d_in[3];
    const float* W1 = (const float*)d_in[4];  const float* b1 = (const float*)d_in[5];
    const float* W2 = (const float*)d_in[6];  const float* b2 = (const float*)d_in[7];
    const float* Wl = (const float*)d_in[8];  const float* bl = (const float*)d_in[9];
    const float* Wp = (const float*)d_in[10]; const float* bp = (const float*)d_in[11];
    const float* Vw1 = (const float*)d_in[12]; const float* Vb1 = (const float*)d_in[13];
    const float* Vw2 = (const float*)d_in[14]; const float* Vb2 = (const float*)d_in[15];
    const float* Vw3 = (const float*)d_in[16]; const float* Vb3 = (const float*)d_in[17];
    const float* Cw1 = (const float*)d_in[18]; const float* Cb1 = (const float*)d_in[19];
    const float* Cw2 = (const float*)d_in[20]; const float* Cb2 = (const float*)d_in[21];

    char* ws = (char*)d_ws;
    int*          gfill   = (int*)(ws + OFF_GFILL);
    int*          arr1    = (int*)(ws + OFF_ARR1);
    int*          arr2    = (int*)(ws + OFF_ARR2);
    int*          arr3    = (int*)(ws + OFF_ARR3);
    float*        pooled8 = (float*)(ws + OFF_POOL8);
    float*        disg    = (float*)(ws + OFF_DIS);
    float*        h1g     = (float*)(ws + OFF_H1G);
    unsigned int* ebuf    = (unsigned int*)(ws + OFF_EBUF);

    const int* srcp = ei;
    const int* dstp = ei + NEDGES;

    hipMemsetAsync(ws, 0, 4096, stream);  /* gfill[512] + arr1/2/3 */

    k_bucket<<<256, 256, 0, stream>>>(srcp, dstp, gfill, ebuf);
    k_gcn<<<512, 1024, 0, stream>>>(x, W1, b1, W2, b2, Wl, bl, Wp, bp,
                                    Vw1, Vb1, Vw2, Vb2, Vw3, Vb3,
                                    Cw1, Cb1, Cw2, Cb2, share,
                                    ebuf, gfill, disg, h1g,
                                    arr1, arr2, arr3, pooled8, (float*)d_out);
}

// Round 7
// 181.302 us; speedup vs baseline: 1.2852x; 1.2852x over previous
//
#include <hip/hip_runtime.h>
#include <hip/hip_fp16.h>
#include <math.h>

#define NEDGES 2097152
#define CAPB   9216    /* per-(graph,quarter) bucket cap: mean 8192, sigma~90 -> +11 sigma */
#define CAPQ   9728    /* per-quarter CSR cap: 8192 + align-pad<=768 + 8.5 sigma           */

/* ws layout (bytes) */
#define OFF_GFILL 0u          /* int[256] per-bucket fill                    */
#define OFF_ARR1  1024u       /* int[64]  dis-exchange flags                 */
#define OFF_ARR2  1280u       /* int[64]  h1-exchange flags                  */
#define OFF_ARR3  1536u       /* int[64]  pool/tail flags                    */
#define OFF_POOL4 2048u       /* float[64*4*32] = 32768 -> 34816             */
#define OFF_DIS   34816u      /* float[65536] = 262144 -> 296960             */
#define OFF_H1G   296960u     /* float[65536*32] = 8388608 -> 8685568        */
#define OFF_EBUF  8685568u    /* uint[256*CAPB] = 9437184 -> 18122752        */

__device__ __forceinline__ float ftanh(float x) {
    float e = __expf(2.f * x);
    return 1.f - 2.f * __builtin_amdgcn_rcpf(e + 1.f);
}

/* read channels 4q..4q+3 of swizzled f16x2 row r */
__device__ __forceinline__ float4 ld4h(const unsigned int* hs, int r, int q) {
    uint2 u = *(const uint2*)(hs + r * 16 + ((q ^ (r & 7)) << 1));
    float2 fa = __half22float2(*(const __half2*)&u.x);
    float2 fb = __half22float2(*(const __half2*)&u.y);
    return make_float4(fa.x, fa.y, fb.x, fb.y);
}
__device__ __forceinline__ uint2 pk4h(float a, float b, float c, float d) {
    __half2 h0 = __floats2half2_rn(a, b);
    __half2 h1 = __floats2half2_rn(c, d);
    return make_uint2(*(unsigned int*)&h0, *(unsigned int*)&h1);
}

/* ---- bucket edges by (graph, dst-quarter): 256 buckets; 1024 threads/block
   (16 waves/CU) for latency hiding. R5-phase-A-proven code. ---- */
__global__ __launch_bounds__(1024) void k_bucket(
        const int* __restrict__ src, const int* __restrict__ dst,
        int* __restrict__ gfill, unsigned int* __restrict__ ebuf) {
    __shared__ unsigned int sorted[8192];
    __shared__ int hist[256], lexcl[256], gbase[256], lfill[256];
    __shared__ int wsum[4];
    int t = threadIdx.x;
    int blk = blockIdx.x;
    int lane = t & 63, wid = t >> 6;

    if (t < 256) { hist[t] = 0; lfill[t] = 0; }
    __syncthreads();

    unsigned int pk[8];
    {
        const int4* s4p = (const int4*)(src + blk * 8192);
        const int4* d4p = (const int4*)(dst + blk * 8192);
        #pragma unroll
        for (int k = 0; k < 2; k++) {
            int4 s4 = s4p[k * 1024 + t];
            int4 d4 = d4p[k * 1024 + t];
            int ss[4] = { s4.x, s4.y, s4.z, s4.w };
            int dd[4] = { d4.x, d4.y, d4.z, d4.w };
            #pragma unroll
            for (int j = 0; j < 4; j++) {
                int gg = ss[j] >> 10;
                /* pack: src_local | dst_local<<10 | g<<20 ; bucket = pk>>18 */
                pk[k * 4 + j] = (unsigned int)((ss[j] & 1023) | ((dd[j] & 1023) << 10) | (gg << 20));
                atomicAdd(&hist[(gg << 2) | ((dd[j] >> 8) & 3)], 1);
            }
        }
    }
    __syncthreads();

    int hA = 0, xxA = 0;
    if (t < 256) {
        hA = hist[t];
        xxA = hA;
        #pragma unroll
        for (int off = 1; off < 64; off <<= 1) {
            int y = __shfl_up(xxA, off, 64);
            if (lane >= off) xxA += y;
        }
        if (lane == 63) wsum[wid] = xxA;
    }
    __syncthreads();
    if (t < 256) {
        int pre = 0;
        for (int w = 0; w < wid; w++) pre += wsum[w];
        lexcl[t] = pre + xxA - hA;
        gbase[t] = atomicAdd(&gfill[t], hA);
    }
    __syncthreads();

    #pragma unroll
    for (int k = 0; k < 8; k++) {
        int b = pk[k] >> 18;
        int pos = lexcl[b] + atomicAdd(&lfill[b], 1);
        sorted[pos] = pk[k];
    }
    __syncthreads();
    #pragma unroll
    for (int k = 0; k < 8; k++) {
        int i = k * 1024 + t;
        unsigned int p = sorted[i];
        int b = p >> 18;
        ebuf[(size_t)b * CAPB + gbase[b] + (i - lexcl[b])] = p;
    }
}

/* ---- quarter-graph GCN (R1-proven structure) with f16-packed LDS hs table
   + folded MLP tail. 256 blocks x 1024 thr, ~89 KB LDS -> 1 block/CU ->
   all 256 blocks co-resident -> flag syncs safe. ---- */
__global__ __launch_bounds__(1024, 1) void k_gcn(
        const float* __restrict__ x,
        const float* __restrict__ W1, const float* __restrict__ b1,
        const float* __restrict__ W2, const float* __restrict__ b2,
        const float* __restrict__ Wl, const float* __restrict__ bl,
        const float* __restrict__ Wp, const float* __restrict__ bp,
        const float* __restrict__ Vw1, const float* __restrict__ Vb1,
        const float* __restrict__ Vw2, const float* __restrict__ Vb2,
        const float* __restrict__ Vw3, const float* __restrict__ Vb3,
        const float* __restrict__ Cw1, const float* __restrict__ Cb1,
        const float* __restrict__ Cw2, const float* __restrict__ Cb2,
        const float* __restrict__ share,
        const unsigned int* __restrict__ ebuf, const int* __restrict__ gfill,
        float* __restrict__ disg, float* __restrict__ h1g,
        int* __restrict__ arr1, int* __restrict__ arr2, int* __restrict__ arr3,
        float* __restrict__ pooled4, float* __restrict__ out) {
    __shared__ unsigned int hsLh[1025 * 16];              /* 65600 B, row 1024 = zeros */
    __shared__ __align__(16) unsigned short lcsr[CAPQ];   /* 19456 B */
    __shared__ int hist[256], lrow[256], lfill[256];
    __shared__ int wsum[4];
    /* ~89 KB -> 1 block/CU */

    int t = threadIdx.x;
    int g = blockIdx.x & 63, part = blockIdx.x >> 6;
    int bkt = (g << 2) | part;
    int cnt = gfill[bkt];
    const unsigned int* eb = ebuf + (size_t)bkt * CAPB;
    int lane = t & 63, wid = t >> 6;

    /* preload x row early; latency overlaps the edge scans */
    float inr[16];
    {
        const float4* in4 = (const float4*)(x + ((size_t)(g << 10) + t) * 16);
        #pragma unroll
        for (int k = 0; k < 4; k++) {
            float4 v = in4[k];
            inr[4*k] = v.x; inr[4*k+1] = v.y; inr[4*k+2] = v.z; inr[4*k+3] = v.w;
        }
    }

    if (t < 256) hist[t] = 0;
    if (t < 16) hsLh[1024 * 16 + t] = 0u;     /* zero row for CSR padding */
    __syncthreads();

    /* pass 1: degree hist over own quarter bucket (~8K edges) */
    for (int i = t; i < cnt; i += 1024) atomicAdd(&hist[(eb[i] >> 10) & 255], 1);
    __syncthreads();

    /* publish this quarter's dis, release flag 1 */
    int dq = 0, r4 = 0;
    if (t < 256) {
        dq = hist[t]; r4 = (dq + 3) & ~3;
        disg[(g << 10) + part * 256 + t] = rsqrtf((float)(dq + 1));
    }
    __syncthreads();  /* drains vmem: disg stores done before release */
    if (t == 0)
        __hip_atomic_fetch_add(arr1 + g, 1, __ATOMIC_RELEASE, __HIP_MEMORY_SCOPE_AGENT);

    /* exclusive scan of 4-aligned degrees -> CSR row starts */
    int xx = r4;
    #pragma unroll
    for (int off = 1; off < 64; off <<= 1) {
        int y = __shfl_up(xx, off, 64);
        if (lane >= off) xx += y;
    }
    if (t < 256 && lane == 63) wsum[wid] = xx;
    __syncthreads();
    if (t < 256) {
        int pre = 0;
        for (int w = 0; w < wid; w++) pre += wsum[w];
        lrow[t] = pre + xx - r4;
        lfill[t] = 0;
    }
    __syncthreads();

    /* pass 2: scatter own bucket into LDS CSR; pad rows to x4 */
    for (int i = t; i < cnt; i += 1024) {
        unsigned int v = eb[i];
        int dl = (v >> 10) & 255;
        int pos = lrow[dl] + atomicAdd(&lfill[dl], 1);
        lcsr[pos] = (unsigned short)(v & 1023);
    }
    if (t < 256) {
        int st = lrow[t];
        for (int i = dq; i < r4; i++) lcsr[st + i] = 1024;
    }

    /* wait for all 4 quarters' dis */
    if (t == 0) {
        while (__hip_atomic_load(arr1 + g, __ATOMIC_RELAXED, __HIP_MEMORY_SCOPE_AGENT) < 4) {}
        (void)__hip_atomic_load(arr1 + g, __ATOMIC_ACQUIRE, __HIP_MEMORY_SCOPE_AGENT);
    }
    __syncthreads();

    float dis_t = disg[(g << 10) + t];
    int sw = t & 7;

    /* stage hs1 = dis * (x @ W1^T) for ALL 1024 nodes, f16x2 swizzled */
    #pragma unroll
    for (int o4 = 0; o4 < 8; o4++) {
        float r[4];
        #pragma unroll
        for (int j = 0; j < 4; j++) {
            int o = o4 * 4 + j;
            float s = 0.f;
            #pragma unroll
            for (int k = 0; k < 16; k++) s += inr[k] * W1[o * 16 + k];
            r[j] = s * dis_t;
        }
        *(uint2*)&hsLh[t * 16 + ((o4 ^ sw) << 1)] = pk4h(r[0], r[1], r[2], r[3]);
    }
    __syncthreads();

    /* layer-1 gather for own 256 nodes, 8 lanes/node; h1 -> global f32 */
    int q = t & 7, grp = t >> 3;
    #pragma unroll
    for (int pass = 0; pass < 2; pass++) {
        int lq = pass * 128 + grp;
        int ln = part * 256 + lq;
        int d = hist[lq];
        float dn = rsqrtf((float)(d + 1));
        int st = lrow[lq];
        float4 acc = ld4h(hsLh, ln, q);
        const ushort4* c4 = (const ushort4*)(lcsr + st);
        int d4 = (d + 3) >> 2;
        for (int i = 0; i < d4; i++) {
            ushort4 ss = c4[i];
            float4 v0 = ld4h(hsLh, ss.x, q);
            float4 v1 = ld4h(hsLh, ss.y, q);
            float4 v2 = ld4h(hsLh, ss.z, q);
            float4 v3 = ld4h(hsLh, ss.w, q);
            acc.x += (v0.x + v1.x) + (v2.x + v3.x);
            acc.y += (v0.y + v1.y) + (v2.y + v3.y);
            acc.z += (v0.z + v1.z) + (v2.z + v3.z);
            acc.w += (v0.w + v1.w) + (v2.w + v3.w);
        }
        float4 bb = ((const float4*)b1)[q];
        float4 r;
        r.x = ftanh(dn * acc.x + bb.x);
        r.y = ftanh(dn * acc.y + bb.y);
        r.z = ftanh(dn * acc.z + bb.z);
        r.w = ftanh(dn * acc.w + bb.w);
        ((float4*)h1g)[((size_t)(g << 10) + ln) * 8 + q] = r;
    }
    __syncthreads();  /* drain h1g stores */
    if (t == 0) {
        __hip_atomic_fetch_add(arr2 + g, 1, __ATOMIC_RELEASE, __HIP_MEMORY_SCOPE_AGENT);
        while (__hip_atomic_load(arr2 + g, __ATOMIC_RELAXED, __HIP_MEMORY_SCOPE_AGENT) < 4) {}
        (void)__hip_atomic_load(arr2 + g, __ATOMIC_ACQUIRE, __HIP_MEMORY_SCOPE_AGENT);
    }
    __syncthreads();

    /* read full h1 row for node t, stage hs2 = dis * (h1 @ W2^T), f16 */
    {
        float r2[32];
        const float4* h4 = (const float4*)(h1g + ((size_t)(g << 10) + t) * 32);
        #pragma unroll
        for (int k = 0; k < 8; k++) {
            float4 v = h4[k];
            r2[4*k] = v.x; r2[4*k+1] = v.y; r2[4*k+2] = v.z; r2[4*k+3] = v.w;
        }
        #pragma unroll
        for (int o4 = 0; o4 < 8; o4++) {
            float r[4];
            #pragma unroll
            for (int j = 0; j < 4; j++) {
                int o = o4 * 4 + j;
                float s = 0.f;
                #pragma unroll
                for (int k = 0; k < 32; k++) s += r2[k] * W2[o * 32 + k];
                r[j] = s * dis_t;
            }
            *(uint2*)&hsLh[t * 16 + ((o4 ^ sw) << 1)] = pk4h(r[0], r[1], r[2], r[3]);
        }
    }
    __syncthreads();

    /* layer-2 gather (same LDS CSR), keep results in registers */
    float4 racc[2];
    #pragma unroll
    for (int pass = 0; pass < 2; pass++) {
        int lq = pass * 128 + grp;
        int ln = part * 256 + lq;
        int d = hist[lq];
        float dn = rsqrtf((float)(d + 1));
        int st = lrow[lq];
        float4 acc = ld4h(hsLh, ln, q);
        const ushort4* c4 = (const ushort4*)(lcsr + st);
        int d4 = (d + 3) >> 2;
        for (int i = 0; i < d4; i++) {
            ushort4 ss = c4[i];
            float4 v0 = ld4h(hsLh, ss.x, q);
            float4 v1 = ld4h(hsLh, ss.y, q);
            float4 v2 = ld4h(hsLh, ss.z, q);
            float4 v3 = ld4h(hsLh, ss.w, q);
            acc.x += (v0.x + v1.x) + (v2.x + v3.x);
            acc.y += (v0.y + v1.y) + (v2.y + v3.y);
            acc.z += (v0.z + v1.z) + (v2.z + v3.z);
            acc.w += (v0.w + v1.w) + (v2.w + v3.w);
        }
        float4 bb = ((const float4*)b2)[q];
        float4 r;
        r.x = ftanh(dn * acc.x + bb.x);
        r.y = ftanh(dn * acc.y + bb.y);
        r.z = ftanh(dn * acc.z + bb.z);
        r.w = ftanh(dn * acc.w + bb.w);
        racc[pass] = r;
    }
    __syncthreads();

    /* write h2 (f16) for own 256 rows */
    #pragma unroll
    for (int pass = 0; pass < 2; pass++) {
        int ln = part * 256 + pass * 128 + grp;
        *(uint2*)&hsLh[ln * 16 + ((q ^ (ln & 7)) << 1)] =
            pk4h(racc[pass].x, racc[pass].y, racc[pass].z, racc[pass].w);
    }
    __syncthreads();

    /* h3 = tanh(h2 @ Wl^T + bl), pool own 256 nodes (32 segs x 8 nodes) */
    int o = t & 31, seg = t >> 5;
    float ps = 0.f;
    {
        float wlr[32];
        #pragma unroll
        for (int k = 0; k < 32; k++) wlr[k] = Wl[o * 32 + k];
        float blv = bl[o];
        #pragma unroll
        for (int j = 0; j < 8; j++) {
            int row = part * 256 + seg * 8 + j;
            float s = blv;
            #pragma unroll
            for (int p2 = 0; p2 < 8; p2++) {
                float4 v = ld4h(hsLh, row, p2);
                s += v.x * wlr[4*p2] + v.y * wlr[4*p2+1] + v.z * wlr[4*p2+2] + v.w * wlr[4*p2+3];
            }
            ps += ftanh(s);
        }
    }
    float* psum = (float*)lcsr;   /* CSR dead now */
    psum[t] = ps;
    __syncthreads();
    if (t < 32) {
        float tot = 0.f;
        for (int s2 = 0; s2 < 32; s2++) tot += psum[s2 * 32 + t];
        pooled4[(g * 4 + part) * 32 + t] = tot;
    }
    __syncthreads();   /* drain pooled4 stores */
    if (t == 0)
        __hip_atomic_fetch_add(arr3 + g, 1, __ATOMIC_RELEASE, __HIP_MEMORY_SCOPE_AGENT);

    /* part-0 block runs the per-graph MLP tail (R5/R6-proven) */
    if (part == 0) {
        if (t == 0) {
            while (__hip_atomic_load(arr3 + g, __ATOMIC_RELAXED, __HIP_MEMORY_SCOPE_AGENT) < 4) {}
            (void)__hip_atomic_load(arr3 + g, __ATOMIC_ACQUIRE, __HIP_MEMORY_SCOPE_AGENT);
        }
        __syncthreads();
        if (t < 32) {
            int j = t;
            float p = pooled4[(g * 4 + 0) * 32 + j] + pooled4[(g * 4 + 1) * 32 + j]
                    + pooled4[(g * 4 + 2) * 32 + j] + pooled4[(g * 4 + 3) * 32 + j];
            float h1v = bp[j];
            #pragma unroll
            for (int k = 0; k < 32; k++) h1v += Wp[j * 32 + k] * __shfl(p, k, 32);
            float s0 = share[g * 64 + j];
            float s1 = share[g * 64 + 32 + j];
            float t1 = Vb1[j];
            #pragma unroll
            for (int k = 0; k < 32; k++) {
                t1 += Vw1[j * 64 + k] * __shfl(s0, k, 32);
                t1 += Vw1[j * 64 + 32 + k] * __shfl(s1, k, 32);
            }
            t1 = tanhf(t1);
            float t2 = Vb2[j];
            #pragma unroll
            for (int k = 0; k < 32; k++) t2 += Vw2[j * 32 + k] * __shfl(t1, k, 32);
            t2 = tanhf(t2);
            float h2v = Vb3[j];
            #pragma unroll
            for (int k = 0; k < 32; k++) h2v += Vw3[j * 32 + k] * __shfl(t2, k, 32);
            float z = Cb1[j];
            #pragma unroll
            for (int k = 0; k < 32; k++) {
                z += Cw1[j * 64 + k] * __shfl(h1v, k, 32);
                z += Cw1[j * 64 + 32 + k] * __shfl(h2v, k, 32);
            }
            z = tanhf(z);
            float v = Cw2[j] * z;
            v += __shfl_down(v, 16, 32); v += __shfl_down(v, 8, 32);
            v += __shfl_down(v, 4, 32);  v += __shfl_down(v, 2, 32);
            v += __shfl_down(v, 1, 32);
            if (j == 0) out[g] = v + Cb2[0];
        }
    }
}

extern "C" void kernel_launch(void* const* d_in, const int* in_sizes, int n_in,
                              void* d_out, int out_size, void* d_ws, size_t ws_size,
                              hipStream_t stream) {
    const float* x     = (const float*)d_in[0];
    const int*   ei    = (const int*)d_in[1];
    const float* share = (const float*)d_in[3];
    const float* W1 = (const float*)d_in[4];  const float* b1 = (const float*)d_in[5];
    const float* W2 = (const float*)d_in[6];  const float* b2 = (const float*)d_in[7];
    const float* Wl = (const float*)d_in[8];  const float* bl = (const float*)d_in[9];
    const float* Wp = (const float*)d_in[10]; const float* bp = (const float*)d_in[11];
    const float* Vw1 = (const float*)d_in[12]; const float* Vb1 = (const float*)d_in[13];
    const float* Vw2 = (const float*)d_in[14]; const float* Vb2 = (const float*)d_in[15];
    const float* Vw3 = (const float*)d_in[16]; const float* Vb3 = (const float*)d_in[17];
    const float* Cw1 = (const float*)d_in[18]; const float* Cb1 = (const float*)d_in[19];
    const float* Cw2 = (const float*)d_in[20]; const float* Cb2 = (const float*)d_in[21];

    char* ws = (char*)d_ws;
    int*          gfill   = (int*)(ws + OFF_GFILL);
    int*          arr1    = (int*)(ws + OFF_ARR1);
    int*          arr2    = (int*)(ws + OFF_ARR2);
    int*          arr3    = (int*)(ws + OFF_ARR3);
    float*        pooled4 = (float*)(ws + OFF_POOL4);
    float*        disg    = (float*)(ws + OFF_DIS);
    float*        h1g     = (float*)(ws + OFF_H1G);
    unsigned int* ebuf    = (unsigned int*)(ws + OFF_EBUF);

    const int* srcp = ei;
    const int* dstp = ei + NEDGES;

    hipMemsetAsync(ws, 0, 2048, stream);  /* gfill + arr1/2/3 */

    k_bucket<<<256, 1024, 0, stream>>>(srcp, dstp, gfill, ebuf);
    k_gcn<<<256, 1024, 0, stream>>>(x, W1, b1, W2, b2, Wl, bl, Wp, bp,
                                    Vw1, Vb1, Vw2, Vb2, Vw3, Vb3,
                                    Cw1, Cb1, Cw2, Cb2, share,
                                    ebuf, gfill, disg, h1g,
                                    arr1, arr2, arr3, pooled4, (float*)d_out);
}